// Round 8
// baseline (346.297 us; speedup 1.0000x reference)
//
#include <hip/hip_runtime.h>

typedef __bf16 bf16x8 __attribute__((ext_vector_type(8)));
typedef float f32x4 __attribute__((ext_vector_type(4)));

#define MFMA(a,b,c) __builtin_amdgcn_mfma_f32_16x16x32_bf16((a),(b),(c),0,0,0)

__device__ __forceinline__ float rcp_(float x){ return __builtin_amdgcn_rcpf(x); }

#define L2E 1.4426950408889634f

// ---------------- prep: fold Whh@Wh_p / Whh@Wh_u, build bf16 B-frag table ----
// Per main-kernel tid (0..255): 22 frags x 8 bf16 = 176 elements.
//   f 0..7  : G1[g][s] = L2E*(Whh @ Wh_p)[n][k]   (x2 extra for g==2)
//   f 8..15 : G2[g][s] = L2E*(Whh @ Wh_u)[n][k]
//   f 16..19: bc[s]  = Wh2[n][k]  (K=128 = [prev|up], unscaled)
//   f 20..21: fc[s]  = Wfc[0][k] - Wfc[1][k] (broadcast over n, unscaled)
__global__ __launch_bounds__(256) void prep_kernel(
    const float* __restrict__ Wh,  const float* __restrict__ Wh2,
    const float* __restrict__ Whh, const float* __restrict__ Wfc,
    __bf16* __restrict__ tbl)
{
  const int idx = blockIdx.x*256 + threadIdx.x;
  if (idx >= 256*176) return;
  const int e = idx & 7, f = (idx >> 3) % 22, t = idx / 176;
  const int w = t >> 6, lane = t & 63, l16 = lane & 15, g8 = (lane >> 4) * 8;
  float val;
  if (f < 16){
    const int g = (f >> 1) & 3, s = f & 1, half = f >> 3;
    const int n = g*64 + w*16 + l16;
    const int k = s*32 + g8 + e;
    const float* whcol = Wh + half*64 + k;
    float acc = 0.f;
    for (int j=0; j<64; ++j) acc += Whh[n*64 + j] * whcol[j*128];
    val = acc * ((g == 2) ? 2.f*L2E : L2E);
  } else if (f < 20){
    const int s = f - 16;
    const int n = w*16 + l16;
    const int k = s*32 + g8 + e;
    val = Wh2[n*128 + k];
  } else {
    const int s = f - 20;
    const int k = s*32 + g8 + e;
    val = Wfc[k] - Wfc[64 + k];
  }
  tbl[t*176 + f*8 + e] = (__bf16)val;
}

// ---------------- main: 256 blocks x 256 threads (4 waves, 16 samples) ------
// TWO independent 8-row groups (batch rows 0-7 / 8-15) advance through the
// recurrence in each t-iteration: their GEMM->activation chains interleave,
// filling each other's ds_read/MFMA/exp latency at 1 wave/SIMD. One barrier
// covers both cells. M-tile rows 8..15 duplicate 0..7; the epilogue splits
// the duplicate halves via cndmask-selects (2 els/lane/group -> 1x VALU).
// Softmax deferred to a parallel end phase via s_d.
__global__ __launch_bounds__(256,1) void lstm2d_kernel(
    const float* __restrict__ x,   const float* __restrict__ Wx,
    const float* __restrict__ Wih,
    const float* __restrict__ bih, const float* __restrict__ bhh,
    const float* __restrict__ bfc,
    const __bf16* __restrict__ tbl,
    float* __restrict__ out)
{
  __shared__ __align__(16) __bf16 s_h[2][16*8*64];  // [grp][col][row][hid] 32 KB
  __shared__ __align__(16) __bf16 s_c[2][16*8*64];  // 32 KB
  __shared__ __align__(16) float  s_xh[256*16];     // [slot][row] 16 KB
  __shared__ __align__(16) float  s_d[256*16];      // [slot][row] 16 KB
  __shared__ unsigned int s_msk[16*8];              // [row][word]
  __shared__ float s_red[256];                      // [grp16][row16] 1 KB

  const int tid  = threadIdx.x;
  const int w    = tid >> 6;
  const int lane = tid & 63;
  const int l16  = lane & 15;
  const int g4   = lane >> 4;
  const int g8   = g4 * 8;
  const int rl   = l16 & 7;
  const bool sel = (g4 >= 2);          // which duplicate half this lane owns

  const float wx0 = Wx[0], wx1 = Wx[1];

  // zero state
  unsigned int* zh = (unsigned int*)s_h;
  unsigned int* zc = (unsigned int*)s_c;
  #pragma unroll
  for (int it=0; it<32; ++it){ zh[tid + it*256] = 0u; zc[tid + it*256] = 0u; }

  // xh precompute (4096 entries)
  const float* xg = x + blockIdx.x * 4096;
  #pragma unroll
  for (int k=0; k<16; ++k){
    const int idx = tid + k*256;
    const int row = idx & 15, slot = idx >> 4;
    const int i = slot >> 4, t = slot & 15;
    const int c   = (i & 1) ? 15 - t : t;
    const int cpc = (i & 1) ? c + 1 : c - 1;
    const float xp = (t > 0) ? xg[row*256 + i*16 + cpc] : 0.f;
    const float xu = (i > 0) ? xg[row*256 + (i-1)*16 + c] : 0.f;
    s_xh[slot*16 + row] = (xp*wx0 + xu*wx1 + 1.f) * 0.5f;
  }
  // mask bits
  if (tid < 128){
    const int row = tid >> 3, wd = tid & 7;
    unsigned int m = 0;
    for (int b=0; b<32; ++b){
      const int slot = wd*32 + b, i = slot >> 4, t = slot & 15;
      const int c = (i & 1) ? 15 - t : t;
      if (xg[row*256 + i*16 + c] > 0.f) m |= (1u << b);
    }
    s_msk[row*8 + wd] = m;
  }

  // weight fragments
  const __bf16* tb = tbl + tid*176;
  bf16x8 G1f[4][2], G2f[4][2], bcf[4], fcB[2];
  #pragma unroll
  for (int g=0; g<4; ++g)
    #pragma unroll
    for (int s=0; s<2; ++s){
      G1f[g][s] = *(const bf16x8*)(tb + (g*2+s)*8);
      G2f[g][s] = *(const bf16x8*)(tb + 64 + (g*2+s)*8);
    }
  #pragma unroll
  for (int s=0; s<4; ++s) bcf[s] = *(const bf16x8*)(tb + 128 + s*8);
  #pragma unroll
  for (int s=0; s<2; ++s) fcB[s] = *(const bf16x8*)(tb + 160 + s*8);

  const float bd = bfc[0] - bfc[1];
  float base_[4], dvec_[4];
  #pragma unroll
  for (int g=0; g<4; ++g){
    const int cg = g*64 + w*16 + l16;
    const float sc = (g == 2) ? 2.f*L2E : L2E;
    base_[g] = (bih[cg] + bhh[cg] + Wih[cg*2+1]) * sc;
    dvec_[g] = (Wih[cg*2+0] - Wih[cg*2+1]) * sc;
  }
  const int colw = w*16 + l16;

  // per-lane LDS offsets (elements); col stride = 512 els
  const int offA0 = rl*64 + ((     g8) ^ (rl << 3));
  const int offA1 = rl*64 + ((32 + g8) ^ (rl << 3));
  const int rsel  = sel ? 2 : 0;
  int stW[2], rowW[2];
  #pragma unroll
  for (int e=0; e<2; ++e){
    const int R = (g4 & 1)*4 + rsel + e;       // batch row (0..7) this lane owns
    rowW[e] = R;
    stW[e]  = R*64 + (colw ^ (R << 3));
  }
  const int xhA = (g4 & 1) * 4;
  const int xhB = 8 + (g4 & 1) * 4;
  const float C2 = -2.f*L2E;

  __syncthreads();

  f32x4 uGA[4], uGB[4], uCA, uCB;   // prefetched up-contributions per group

  for (int i=0; i<16; ++i){
    const int dir = i & 1;
    const int slot0 = i*16;

    // ---- prologue: up contributions for t=0 of both groups ----
    {
      const int bu = (dir ? 15 : 0) << 9;
      bf16x8 hA0 = *(const bf16x8*)(s_h[0] + bu + offA0);
      bf16x8 hA1 = *(const bf16x8*)(s_h[0] + bu + offA1);
      bf16x8 cA0 = *(const bf16x8*)(s_c[0] + bu + offA0);
      bf16x8 cA1 = *(const bf16x8*)(s_c[0] + bu + offA1);
      bf16x8 hB0 = *(const bf16x8*)(s_h[1] + bu + offA0);
      bf16x8 hB1 = *(const bf16x8*)(s_h[1] + bu + offA1);
      bf16x8 cB0 = *(const bf16x8*)(s_c[1] + bu + offA0);
      bf16x8 cB1 = *(const bf16x8*)(s_c[1] + bu + offA1);
      const float4 xa = *(const float4*)(s_xh + slot0*16 + xhA);
      const float4 xb = *(const float4*)(s_xh + slot0*16 + xhB);
      #pragma unroll
      for (int g=0; g<4; ++g){
        #pragma unroll
        for (int r=0;r<4;++r){
          uGA[g][r] = base_[g] + (&xa.x)[r] * dvec_[g];
          uGB[g][r] = base_[g] + (&xb.x)[r] * dvec_[g];
        }
        uGA[g] = MFMA(hA0, G2f[g][0], uGA[g]); uGA[g] = MFMA(hA1, G2f[g][1], uGA[g]);
        uGB[g] = MFMA(hB0, G2f[g][0], uGB[g]); uGB[g] = MFMA(hB1, G2f[g][1], uGB[g]);
      }
      f32x4 z = {0.f,0.f,0.f,0.f};
      uCA = MFMA(cA0, bcf[2], z);  uCA = MFMA(cA1, bcf[3], uCA);
      uCB = MFMA(cB0, bcf[2], z);  uCB = MFMA(cB1, bcf[3], uCB);
      if (i > 0){
        if (w == 3){
          f32x4 fz = {bd,bd,bd,bd};
          fz = MFMA(hA0, fcB[0], fz);
          f32x4 aF = MFMA(hA1, fcB[1], fz);
          if (l16 == 0){
            s_d[(slot0-1)*16 + rowW[0]] = aF[rsel];
            s_d[(slot0-1)*16 + rowW[1]] = aF[rsel+1];
          }
        }
        if (w == 1){
          f32x4 fz = {bd,bd,bd,bd};
          fz = MFMA(hB0, fcB[0], fz);
          f32x4 aF = MFMA(hB1, fcB[1], fz);
          if (l16 == 0){
            s_d[(slot0-1)*16 + 8 + rowW[0]] = aF[rsel];
            s_d[(slot0-1)*16 + 8 + rowW[1]] = aF[rsel+1];
          }
        }
      }
    }

    for (int t=0; t<16; ++t){
      const int c    = dir ? 15 - t : t;
      const int slot = slot0 + t;

      // ---------- phase 1: gates + c_inter, both groups ----------
      f32x4 gA[4], gB[4], aCA, aCB;
      if (t > 0){
        const int bp = (dir ? c + 1 : c - 1) << 9;
        bf16x8 aA0 = *(const bf16x8*)(s_h[0] + bp + offA0);
        bf16x8 aA1 = *(const bf16x8*)(s_h[0] + bp + offA1);
        bf16x8 qA0 = *(const bf16x8*)(s_c[0] + bp + offA0);
        bf16x8 qA1 = *(const bf16x8*)(s_c[0] + bp + offA1);
        bf16x8 aB0 = *(const bf16x8*)(s_h[1] + bp + offA0);
        bf16x8 aB1 = *(const bf16x8*)(s_h[1] + bp + offA1);
        bf16x8 qB0 = *(const bf16x8*)(s_c[1] + bp + offA0);
        bf16x8 qB1 = *(const bf16x8*)(s_c[1] + bp + offA1);
        #pragma unroll
        for (int g=0; g<4; ++g){
          gA[g] = MFMA(aA0, G1f[g][0], uGA[g]); gA[g] = MFMA(aA1, G1f[g][1], gA[g]);
          gB[g] = MFMA(aB0, G1f[g][0], uGB[g]); gB[g] = MFMA(aB1, G1f[g][1], gB[g]);
        }
        aCA = MFMA(qA0, bcf[0], uCA); aCA = MFMA(qA1, bcf[1], aCA);
        aCB = MFMA(qB0, bcf[0], uCB); aCB = MFMA(qB1, bcf[1], aCB);
        const int fw = (t - 1) & 3;
        if (w == fw){
          f32x4 fz = {bd,bd,bd,bd};
          fz = MFMA(aA0, fcB[0], fz);
          f32x4 aF = MFMA(aA1, fcB[1], fz);
          if (l16 == 0){
            s_d[(slot-1)*16 + rowW[0]] = aF[rsel];
            s_d[(slot-1)*16 + rowW[1]] = aF[rsel+1];
          }
        }
        if (w == (fw ^ 2)){
          f32x4 fz = {bd,bd,bd,bd};
          fz = MFMA(aB0, fcB[0], fz);
          f32x4 aF = MFMA(aB1, fcB[1], fz);
          if (l16 == 0){
            s_d[(slot-1)*16 + 8 + rowW[0]] = aF[rsel];
            s_d[(slot-1)*16 + 8 + rowW[1]] = aF[rsel+1];
          }
        }
      } else {
        #pragma unroll
        for (int g=0; g<4; ++g){ gA[g] = uGA[g]; gB[g] = uGB[g]; }
        aCA = uCA; aCB = uCB;
      }

      // ---------- prefetch next slot's up contributions ----------
      if (t < 15){
        const int bu = (dir ? 14 - t : t + 1) << 9;
        bf16x8 hA0 = *(const bf16x8*)(s_h[0] + bu + offA0);
        bf16x8 hA1 = *(const bf16x8*)(s_h[0] + bu + offA1);
        bf16x8 cA0 = *(const bf16x8*)(s_c[0] + bu + offA0);
        bf16x8 cA1 = *(const bf16x8*)(s_c[0] + bu + offA1);
        bf16x8 hB0 = *(const bf16x8*)(s_h[1] + bu + offA0);
        bf16x8 hB1 = *(const bf16x8*)(s_h[1] + bu + offA1);
        bf16x8 cB0 = *(const bf16x8*)(s_c[1] + bu + offA0);
        bf16x8 cB1 = *(const bf16x8*)(s_c[1] + bu + offA1);
        const float4 xa = *(const float4*)(s_xh + (slot+1)*16 + xhA);
        const float4 xb = *(const float4*)(s_xh + (slot+1)*16 + xhB);
        #pragma unroll
        for (int g=0; g<4; ++g){
          #pragma unroll
          for (int r=0;r<4;++r){
            uGA[g][r] = base_[g] + (&xa.x)[r] * dvec_[g];
            uGB[g][r] = base_[g] + (&xb.x)[r] * dvec_[g];
          }
          uGA[g] = MFMA(hA0, G2f[g][0], uGA[g]); uGA[g] = MFMA(hA1, G2f[g][1], uGA[g]);
          uGB[g] = MFMA(hB0, G2f[g][0], uGB[g]); uGB[g] = MFMA(hB1, G2f[g][1], uGB[g]);
        }
        f32x4 z = {0.f,0.f,0.f,0.f};
        uCA = MFMA(cA0, bcf[2], z);  uCA = MFMA(cA1, bcf[3], uCA);
        uCB = MFMA(cB0, bcf[2], z);  uCB = MFMA(cB1, bcf[3], uCB);
      }

      // ---------- epilogue: split halves via selects, 2 els/lane/group ----
      const int cb = c << 9;
      #pragma unroll
      for (int e=0; e<2; ++e){
        // group A
        {
          const float ig = sel ? gA[0][2+e] : gA[0][e];
          const float fg = sel ? gA[1][2+e] : gA[1][e];
          const float gg = sel ? gA[2][2+e] : gA[2][e];
          const float og = sel ? gA[3][2+e] : gA[3][e];
          const float cI = sel ? aCA[2+e]   : aCA[e];
          const float si = rcp_(1.f + exp2f(-ig));
          const float sf = rcp_(1.f + exp2f(-fg));
          const float tg = 2.f * rcp_(1.f + exp2f(-gg)) - 1.f;
          const float cn = sf*cI + si*tg;
          const float so = rcp_(1.f + exp2f(-og));
          const float tc = 2.f * rcp_(1.f + exp2f(C2*cn)) - 1.f;
          const float hn = so * tc;
          s_h[0][cb + stW[e]] = (__bf16)hn;
          s_c[0][cb + stW[e]] = (__bf16)cn;
        }
        // group B
        {
          const float ig = sel ? gB[0][2+e] : gB[0][e];
          const float fg = sel ? gB[1][2+e] : gB[1][e];
          const float gg = sel ? gB[2][2+e] : gB[2][e];
          const float og = sel ? gB[3][2+e] : gB[3][e];
          const float cI = sel ? aCB[2+e]   : aCB[e];
          const float si = rcp_(1.f + exp2f(-ig));
          const float sf = rcp_(1.f + exp2f(-fg));
          const float tg = 2.f * rcp_(1.f + exp2f(-gg)) - 1.f;
          const float cn = sf*cI + si*tg;
          const float so = rcp_(1.f + exp2f(-og));
          const float tc = 2.f * rcp_(1.f + exp2f(C2*cn)) - 1.f;
          const float hn = so * tc;
          s_h[1][cb + stW[e]] = (__bf16)hn;
          s_c[1][cb + stW[e]] = (__bf16)cn;
        }
      }

      __syncthreads();
    }
  }

  // d(255): slot 255 ends at column 0, both groups
  if (w == 3){
    bf16x8 a0 = *(const bf16x8*)(s_h[0] + offA0);
    bf16x8 a1 = *(const bf16x8*)(s_h[0] + offA1);
    f32x4 fz = {bd,bd,bd,bd};
    fz = MFMA(a0, fcB[0], fz);
    f32x4 aF = MFMA(a1, fcB[1], fz);
    if (l16 == 0){
      s_d[255*16 + rowW[0]] = aF[rsel];
      s_d[255*16 + rowW[1]] = aF[rsel+1];
    }
  }
  if (w == 1){
    bf16x8 a0 = *(const bf16x8*)(s_h[1] + offA0);
    bf16x8 a1 = *(const bf16x8*)(s_h[1] + offA1);
    f32x4 fz = {bd,bd,bd,bd};
    fz = MFMA(a0, fcB[0], fz);
    f32x4 aF = MFMA(a1, fcB[1], fz);
    if (l16 == 0){
      s_d[255*16 + 8 + rowW[0]] = aF[rsel];
      s_d[255*16 + 8 + rowW[1]] = aF[rsel+1];
    }
  }
  __syncthreads();

  // ---------- end phase: all 4096 log-softmax terms in parallel ----------
  {
    const int row = tid & 15, grp = tid >> 4;   // 16 groups x 16 slots
    float lpp = 0.f;
    #pragma unroll
    for (int e=0; e<16; ++e){
      const int slot = grp*16 + e;
      const float d = s_d[slot*16 + row];
      const int msk = (s_msk[row*8 + (slot >> 5)] >> (slot & 31)) & 1;
      const float zz = msk ? -d : d;
      lpp -= __logf(1.f + __expf(zz));
    }
    s_red[grp*16 + row] = lpp;
  }
  __syncthreads();
  if (tid < 16){
    const int row = tid;
    float lp = 0.f;
    #pragma unroll
    for (int g=0; g<16; ++g) lp += s_red[g*16 + row];
    int aa = 0;
    #pragma unroll
    for (int wd=0; wd<8; ++wd) aa += __popc(s_msk[row*8 + wd]);
    const int m255 = (s_msk[row*8 + 7] >> 31) & 1;
    if (aa == 1 && m255){
      const float d = s_d[255*16 + row];
      lp += __logf(1.f + __expf(-d));   // remove contrib (factor = 1 - mask)
    }
    out[blockIdx.x*16 + row] = lp;
  }
}

extern "C" void kernel_launch(void* const* d_in, const int* in_sizes, int n_in,
                              void* d_out, int out_size, void* d_ws, size_t ws_size,
                              hipStream_t stream) {
  const float* x   = (const float*)d_in[0];
  const float* Wx  = (const float*)d_in[1];
  const float* Wh  = (const float*)d_in[2];
  const float* Wh2 = (const float*)d_in[3];
  const float* Wih = (const float*)d_in[4];
  const float* Whh = (const float*)d_in[5];
  const float* bih = (const float*)d_in[6];
  const float* bhh = (const float*)d_in[7];
  const float* Wfc = (const float*)d_in[8];
  const float* bfc = (const float*)d_in[9];
  float* out = (float*)d_out;
  __bf16* tbl = (__bf16*)d_ws;   // 256*176*2 = 90112 B

  prep_kernel<<<dim3(176), dim3(256), 0, stream>>>(Wh, Wh2, Whh, Wfc, tbl);
  lstm2d_kernel<<<dim3(256), dim3(256), 0, stream>>>(
      x, Wx, Wih, bih, bhh, bfc, tbl, out);
}